// Round 16
// baseline (509.139 us; speedup 1.0000x reference)
//
#include <hip/hip_runtime.h>

// LiquidNeuralNetwork: B=512, S=1024, IN=16, HID=64, OUT=1.
// r0-r15 established: the serial wave's step wall (~325ns) is exposed
// dependency latency, not issue (r15: -45 insts -> no change; r8 ran the
// same eval at 169ns when 4 evals/step gave it independent work to hide
// stalls). Serial-in-time is a dead end at ~300+ us.
//
// Round 16: PICARD ITERATION -- parallelize time. h_{j+1} = a*h_j + G(h_j)
// is contractive: per chunk of K=128 steps one sweep contracts error by
// kappa ~ ||Whh||*K*dt ~ 0.02. Per chunk: guess h frozen at h0 (err ~0.01),
// then 3x { eval G at all 128 sites IN PARALLEL (4 waves x 32 sites, plain
// LDS-broadcast eval: 8 ds_read_b128 + 32 fdot, no cross-lane ops) ->
// scan h (wave0, 1 fma/step, in-place into G) -> refresh Tf=f16(tanh h) }.
// Error after 3 sweeps ~1e-7, four orders below the f16 weight floor that
// pinned absmax at 2^-16 all session. Chunks chain exactly (f32 h carry);
// the fixed point is the same f16-fdot map as the serial kernels.
// LDS: Tf 16K + CB 32K + G 32K = 80KB exactly -> 2 blocks/CU.

constexpr int HID  = 64;
constexpr int INF  = 16;
constexpr int SLEN = 1024;
constexpr int BATCH = 512;
constexpr int K    = 128;            // chunk steps
constexpr int NPIC = 3;              // Picard sweeps per chunk

typedef __fp16 h2_t __attribute__((ext_vector_type(2)));

__device__ __forceinline__ float fdot(unsigned a, h2_t w, float acc) {
    return __builtin_amdgcn_fdot2(__builtin_bit_cast(h2_t, a), w, acc, false);
}

__device__ __forceinline__ float fast_tanh(float x) {
    // tanh(x) = 1 - 2/(e^{2x}+1); exact limits at +/-inf, no clamp needed.
    float e = __builtin_amdgcn_exp2f(x * 2.8853900817779268f); // 2*log2(e)
    float r = __builtin_amdgcn_rcpf(e + 1.0f);
    return fmaf(-2.0f, r, 1.0f);
}

// -expm1(-z) by series, exact to ~1e-17 for z ~ 1e-3 (avoids 1-exp cancel)
__device__ __forceinline__ float beta_of(float z) {
    return z * (1.0f - z * (0.5f - z * ((1.0f/6.0f) - z * (1.0f/24.0f))));
}

__global__ __launch_bounds__(256, 2) void lnn_picard_kernel(
    const float* __restrict__ x,
    const float* __restrict__ W_in,
    const float* __restrict__ b_in,
    const float* __restrict__ W_hh,
    const float* __restrict__ W_ih,
    const float* __restrict__ bias,
    const float* __restrict__ tau,
    const float* __restrict__ W_out,
    const float* __restrict__ b_out,
    float* __restrict__ out)
{
    const int tid  = threadIdx.x;
    const int lane = tid & 63;           // hidden index
    const int wid  = tid >> 6;           // wave id 0..3
    const int b    = blockIdx.x;         // batch index

    __shared__ __fp16 Tf[K][HID];        // 16 KB: f16 tanh of trajectory guess
    __shared__ float  CB[K][HID];        // 32 KB: beta*c per site
    __shared__ float  G [K][HID];        // 32 KB: G, then h after scan

    // --- per-lane setup (each wave redundantly) -----------------------------
    float Wc[INF];
    #pragma unroll
    for (int k = 0; k < INF; ++k) Wc[k] = 0.0f;
    float bcomb = 0.0f;
    for (int j = 0; j < HID; ++j) {
        float wij = W_ih[lane * HID + j];
        bcomb = fmaf(wij, b_in[j], bcomb);
        #pragma unroll
        for (int k = 0; k < INF; ++k) Wc[k] = fmaf(wij, W_in[j * INF + k], Wc[k]);
    }
    const float cbase = bcomb + bias[lane];
    const float bo    = b_out[0];
    const float wo    = W_out[lane];

    const float hsub  = 1.0f / 1023.0f;
    const float rtau  = 1.0f / tau[lane];
    const float beta  = beta_of(hsub * rtau);    // 1 - e^{-dt/tau}
    const float alpha = 1.0f - beta;             // e^{-dt/tau}

    // wh: lane's own W_hh row, beta-folded, f16 pairs (r0-proven layout:
    // wh[4q+p] pairs elements (8q+2p, 8q+2p+1) <-> uint4 word p of t4[q])
    h2_t wh[HID / 2];
    {
        const float4* w4 = (const float4*)(W_hh + lane * HID);
        #pragma unroll
        for (int q = 0; q < HID / 4; ++q) {
            float4 v = w4[q];
            wh[2*q+0] = __builtin_amdgcn_cvt_pkrtz(v.x * beta, v.y * beta);
            wh[2*q+1] = __builtin_amdgcn_cvt_pkrtz(v.z * beta, v.w * beta);
        }
    }

    if (tid == 0) out[(size_t)b * SLEN] = bo;    // step 0: dt=0, h=0

    float h0 = 0.0f;                     // lane's h at chunk start (all waves)

    for (int ch = 0; ch < (SLEN - 1 + K - 1) / K; ++ch) {
        const int sbase = ch * K + 1;                    // first step index
        const int ns    = min(K, (SLEN - 1) - ch * K);   // 128 (last: 127)

        // --- proj: CB[j][lane] = beta*(Wc . x[sbase+j] + cbase) ------------
        for (int jj = 0; jj < 32; ++jj) {
            int j = wid * 32 + jj;
            if (j < ns) {
                const float4* xs =
                    (const float4*)(x + ((size_t)b * SLEN + sbase + j) * INF);
                float4 p0 = xs[0], p1 = xs[1], p2 = xs[2], p3 = xs[3];
                float cA = fmaf(p0.x, Wc[0], fmaf(p0.y, Wc[1],
                           fmaf(p0.z, Wc[2], fmaf(p0.w, Wc[3], cbase))));
                float cB = fmaf(p1.x, Wc[4], fmaf(p1.y, Wc[5],
                           fmaf(p1.z, Wc[6], p1.w * Wc[7])));
                float cC = fmaf(p2.x, Wc[8], fmaf(p2.y, Wc[9],
                           fmaf(p2.z, Wc[10], p2.w * Wc[11])));
                float cD = fmaf(p3.x, Wc[12], fmaf(p3.y, Wc[13],
                           fmaf(p3.z, Wc[14], p3.w * Wc[15])));
                CB[j][lane] = ((cA + cB) + (cC + cD)) * beta;
            }
        }
        // --- init guess: Tf[j] = f16(tanh(h0)) for all sites ---------------
        {
            __fp16 t0 = (__fp16)fast_tanh(h0);
            for (int jj = 0; jj < 32; ++jj) {
                int j = wid * 32 + jj;
                if (j < ns) Tf[j][lane] = t0;
            }
        }
        __syncthreads();

        // --- Picard sweeps -------------------------------------------------
        for (int it = 0; it < NPIC; ++it) {
            // eval: G[j][lane] = CB[j][lane] + sum_m wh[m] . Tf[j][m]
            for (int jj = 0; jj < 32; ++jj) {
                int j = wid * 32 + jj;
                if (j < ns) {
                    const uint4* t4 = (const uint4*)Tf[j];
                    float a0 = CB[j][lane], a1 = 0.f, a2 = 0.f, a3 = 0.f;
                    #pragma unroll
                    for (int q = 0; q < 8; ++q) {
                        uint4 r = t4[q];
                        a0 = fdot(r.x, wh[4*q+0], a0);
                        a1 = fdot(r.y, wh[4*q+1], a1);
                        a2 = fdot(r.z, wh[4*q+2], a2);
                        a3 = fdot(r.w, wh[4*q+3], a3);
                    }
                    G[j][lane] = (a0 + a1) + (a2 + a3);
                }
            }
            __syncthreads();

            // scan (wave 0): G[j] <- h_{j+1} = alpha*h_j + G[j], in place
            if (wid == 0) {
                float h = h0;
                float g0 = G[0][lane];
                for (int j = 0; j < ns; ++j) {
                    float gv = g0;
                    if (j + 1 < ns) g0 = G[j + 1][lane];
                    h = fmaf(alpha, h, gv);
                    G[j][lane] = h;
                }
            }
            __syncthreads();

            // refresh trajectory (skip after last sweep):
            // Tf[j] = f16(tanh(H[j])); H[0]=h0 (unchanged), H[j>=1]=G[j-1]
            if (it < NPIC - 1) {
                for (int jj = 0; jj < 32; ++jj) {
                    int j = wid * 32 + jj;
                    if (j >= 1 && j < ns)
                        Tf[j][lane] = (__fp16)fast_tanh(G[j - 1][lane]);
                }
                __syncthreads();
            }
        }

        // --- odot: out[sbase+j] = bo + sum_i wo_i * f16(tanh(h_{sbase+j})) -
        for (int jj = 0; jj < 32; ++jj) {
            int j = wid * 32 + jj;
            if (j < ns) {
                float t = (float)(__fp16)fast_tanh(G[j][lane]);
                float v = t * wo;
                #pragma unroll
                for (int m = 32; m >= 1; m >>= 1) v += __shfl_xor(v, m, 64);
                if (lane == 0) out[(size_t)b * SLEN + sbase + j] = v + bo;
            }
        }

        // --- carry chunk-final h (f32, exact) ------------------------------
        h0 = G[ns - 1][lane];
        __syncthreads();                 // G/CB/Tf safe to overwrite
    }
}

extern "C" void kernel_launch(void* const* d_in, const int* in_sizes, int n_in,
                              void* d_out, int out_size, void* d_ws, size_t ws_size,
                              hipStream_t stream) {
    const float* x     = (const float*)d_in[0];
    const float* W_in  = (const float*)d_in[1];
    const float* b_in  = (const float*)d_in[2];
    const float* W_hh  = (const float*)d_in[3];
    const float* W_ih  = (const float*)d_in[4];
    const float* bias  = (const float*)d_in[5];
    const float* tau   = (const float*)d_in[6];
    const float* W_out = (const float*)d_in[7];
    const float* b_out = (const float*)d_in[8];
    float* out = (float*)d_out;

    lnn_picard_kernel<<<BATCH, 256, 0, stream>>>(x, W_in, b_in, W_hh, W_ih,
                                                 bias, tau, W_out, b_out, out);
}

// Round 17
// 387.585 us; speedup vs baseline: 1.3136x; 1.3136x over previous
//
#include <hip/hip_runtime.h>

// LiquidNeuralNetwork: B=512, S=1024, IN=16, HID=64, OUT=1.
// r16 proved Picard parallel-in-time converges to the bit-identical fixed
// point (3 sweeps, chunk K=128, contraction kappa~0.02) but was VALU-
// throughput-bound on 3x redundant matvec (484us, VALUBusy 45%).
//
// Round 17: the Picard eval is a dense [128x64]x[64x64] GEMM over
// INDEPENDENT sites -> matrix cores. Per sweep per wave (8 waves, 16-site
// tiles): eval = 2 LDS b128 A-loads + 8 mfma_f32_16x16x32_f16 (B = beta-
// folded Whh^T fragments in regs; A/B share the same lane->k slot map so
// any internal k-order cancels -- principle hardware-verified by r9's
// integer self-test). Scan two-level: 16-step local scan per wave +
// per-wave <=7-step combine (alpha^16 propagator) + fixup H=L+alpha^(m+1)E
// + tanh refresh. LDS exactly 80KB (Tf 16K + CB 32K + G 32K) -> 2 blk/CU.
// Full integer self-test (all 128x64 cells, asymmetric payloads) gates the
// MFMA path; fallback = r16-proven VALU eval in the same skeleton.

constexpr int HID  = 64;
constexpr int INF  = 16;
constexpr int SLEN = 1024;
constexpr int BATCH = 512;
constexpr int K    = 128;            // chunk steps
constexpr int NPIC = 3;              // Picard sweeps per chunk

typedef __fp16 h2_t   __attribute__((ext_vector_type(2)));
typedef __fp16 f16x8_t __attribute__((ext_vector_type(8)));
typedef float  f32x4_t __attribute__((ext_vector_type(4)));

#if __has_builtin(__builtin_amdgcn_mfma_f32_16x16x32_f16)
#define HAVE_MFMA16 1
#else
#define HAVE_MFMA16 0
#endif

__device__ __forceinline__ float fdot(unsigned a, h2_t w, float acc) {
    return __builtin_amdgcn_fdot2(__builtin_bit_cast(h2_t, a), w, acc, false);
}

__device__ __forceinline__ float fast_tanh(float x) {
    // tanh(x) = 1 - 2/(e^{2x}+1); exact limits at +/-inf, no clamp needed.
    float e = __builtin_amdgcn_exp2f(x * 2.8853900817779268f); // 2*log2(e)
    float r = __builtin_amdgcn_rcpf(e + 1.0f);
    return fmaf(-2.0f, r, 1.0f);
}

// -expm1(-z) by series, exact to ~1e-17 for z ~ 1e-3 (avoids 1-exp cancel)
__device__ __forceinline__ float beta_of(float z) {
    return z * (1.0f - z * (0.5f - z * ((1.0f/6.0f) - z * (1.0f/24.0f))));
}

__global__ __launch_bounds__(512) void lnn_picard_mfma_kernel(
    const float* __restrict__ x,
    const float* __restrict__ W_in,
    const float* __restrict__ b_in,
    const float* __restrict__ W_hh,
    const float* __restrict__ W_ih,
    const float* __restrict__ bias,
    const float* __restrict__ tau,
    const float* __restrict__ W_out,
    const float* __restrict__ b_out,
    float* __restrict__ out)
{
    const int tid  = threadIdx.x;
    const int lane = tid & 63;           // hidden index
    const int wid  = tid >> 6;           // wave id 0..7 (16-site tile each)
    const int b    = blockIdx.x;         // batch index
    const int kg   = lane >> 4;          // k-group 0..3
    const int ln   = lane & 15;          // sub-index 0..15

    __shared__ __fp16 Tf[K][HID];        // 16 KB: f16 tanh of trajectory
    __shared__ float  CB[K][HID];        // 32 KB: beta*c per site
    __shared__ float  G [K][HID];        // 32 KB: eval out, then h after scan
                                         // total exactly 80 KB -> 2 blk/CU

    // --- per-lane setup -----------------------------------------------------
    float Wc[INF];
    #pragma unroll
    for (int k = 0; k < INF; ++k) Wc[k] = 0.0f;
    float bcomb = 0.0f;
    for (int j = 0; j < HID; ++j) {
        float wij = W_ih[lane * HID + j];
        bcomb = fmaf(wij, b_in[j], bcomb);
        #pragma unroll
        for (int k = 0; k < INF; ++k) Wc[k] = fmaf(wij, W_in[j * INF + k], Wc[k]);
    }
    const float cbase = bcomb + bias[lane];
    const float bo    = b_out[0];
    const float wo    = W_out[lane];

    const float hsub  = 1.0f / 1023.0f;
    const float rtau  = 1.0f / tau[lane];
    const float beta  = beta_of(hsub * rtau);    // 1 - e^{-dt/tau}
    const float alpha = 1.0f - beta;             // e^{-dt/tau}
    float a2 = alpha * alpha, a4 = a2 * a2, a8 = a4 * a4;
    const float a16 = a8 * a8;                   // tile propagator

    // --- MFMA path: fragments + end-to-end integer self-test ---------------
    bool mfok = false;
#if HAVE_MFMA16
    f16x8_t Bw[4][2];                    // B frags: [col-tile c][k-chunk kc]
    {
        // test pattern: Tf[j][i] = ((j*5+i*3)&7)-3 ; Wt(i,m) = ((i*3+m*7)&7)-3
        #pragma unroll
        for (int m = 0; m < 16; ++m) {
            int j = 16 * wid + m;
            Tf[j][lane] = (__fp16)(float)(((j * 5 + lane * 3) & 7) - 3);
        }
        #pragma unroll
        for (int c = 0; c < 4; ++c)
            #pragma unroll
            for (int kc = 0; kc < 2; ++kc) {
                int col = 16 * c + ln;
                #pragma unroll
                for (int e = 0; e < 8; ++e) {
                    int m = 32 * kc + 8 * kg + e;    // our slot->k map
                    Bw[c][kc][e] = (__fp16)(float)(((col * 3 + m * 7) & 7) - 3);
                }
            }
        __syncthreads();
        // eval (same code as production): A mirrors the slot->k map
        {
            f32x4_t acc[4];
            #pragma unroll
            for (int c = 0; c < 4; ++c) acc[c] = (f32x4_t){0.f, 0.f, 0.f, 0.f};
            const uint4* rowp = (const uint4*)(&Tf[16 * wid + ln][0]);
            #pragma unroll
            for (int kc = 0; kc < 2; ++kc) {
                f16x8_t A = __builtin_bit_cast(f16x8_t, rowp[4 * kc + kg]);
                #pragma unroll
                for (int c = 0; c < 4; ++c)
                    acc[c] = __builtin_amdgcn_mfma_f32_16x16x32_f16(
                        A, Bw[c][kc], acc[c], 0, 0, 0);
            }
            #pragma unroll
            for (int c = 0; c < 4; ++c)
                #pragma unroll
                for (int r = 0; r < 4; ++r)
                    G[16 * wid + 4 * kg + r][16 * c + ln] = acc[c][r];
        }
        // verify every cell this lane will consume: (j=16w+m, i=lane)
        int ok = 1;
        for (int m = 0; m < 16; ++m) {
            int j = 16 * wid + m;
            int ref = 0;
            for (int mm = 0; mm < HID; ++mm)
                ref += (((lane * 3 + mm * 7) & 7) - 3)
                     * (((j * 5 + mm * 3) & 7) - 3);
            ok &= (G[j][lane] == (float)ref);
        }
        mfok = (__syncthreads_and(ok) != 0);
        if (mfok) {
            // real B: Bw[c][kc][e] = Whh[col][m]*beta_col (k map mirrored)
            #pragma unroll
            for (int c = 0; c < 4; ++c) {
                int col = 16 * c + ln;
                float bcol = beta_of(hsub * (1.0f / tau[col]));
                #pragma unroll
                for (int kc = 0; kc < 2; ++kc)
                    #pragma unroll
                    for (int e = 0; e < 8; ++e) {
                        int m = 32 * kc + 8 * kg + e;
                        Bw[c][kc][e] = (__fp16)(W_hh[col * HID + m] * bcol);
                    }
            }
        }
    }
#endif
    // fallback weights (lane's own row, beta-folded, in Tf memory order)
    h2_t wh[HID / 2];
    if (!mfok) {
        const float4* w4 = (const float4*)(W_hh + lane * HID);
        #pragma unroll
        for (int q = 0; q < HID / 4; ++q) {
            float4 v = w4[q];
            wh[2*q+0] = __builtin_amdgcn_cvt_pkrtz(v.x * beta, v.y * beta);
            wh[2*q+1] = __builtin_amdgcn_cvt_pkrtz(v.z * beta, v.w * beta);
        }
    }

    if (tid == 0) out[(size_t)b * SLEN] = bo;    // step 0: dt=0, h=0

    float h0 = 0.0f;                     // h at chunk start (all lanes/waves)

    for (int ch = 0; ch < (SLEN - 1 + K - 1) / K; ++ch) {
        const int sbase = ch * K + 1;
        const int ns    = min(K, (SLEN - 1) - ch * K);   // 128 (last: 127)

        // --- proj + trajectory init (wave-local rows) ----------------------
        {
            __fp16 t0 = (__fp16)fast_tanh(h0);
            for (int m = 0; m < 16; ++m) {
                int j = 16 * wid + m;
                if (j < ns) {
                    const float4* xs =
                        (const float4*)(x + ((size_t)b * SLEN + sbase + j) * INF);
                    float4 p0 = xs[0], p1 = xs[1], p2 = xs[2], p3 = xs[3];
                    float cA = fmaf(p0.x, Wc[0], fmaf(p0.y, Wc[1],
                               fmaf(p0.z, Wc[2], fmaf(p0.w, Wc[3], cbase))));
                    float cB = fmaf(p1.x, Wc[4], fmaf(p1.y, Wc[5],
                               fmaf(p1.z, Wc[6], p1.w * Wc[7])));
                    float cC = fmaf(p2.x, Wc[8], fmaf(p2.y, Wc[9],
                               fmaf(p2.z, Wc[10], p2.w * Wc[11])));
                    float cD = fmaf(p3.x, Wc[12], fmaf(p3.y, Wc[13],
                               fmaf(p3.z, Wc[14], p3.w * Wc[15])));
                    CB[j][lane] = ((cA + cB) + (cC + cD)) * beta;
                    Tf[j][lane] = t0;
                }
            }
        }
        __syncthreads();

        // --- Picard sweeps -------------------------------------------------
        for (int it = 0; it < NPIC; ++it) {
            // eval: G[j][i] = sum_m Whh_b[i][m] * Tf[j][m]  (CB added in scan)
#if HAVE_MFMA16
            if (mfok) {
                f32x4_t acc[4];
                #pragma unroll
                for (int c = 0; c < 4; ++c) acc[c] = (f32x4_t){0.f,0.f,0.f,0.f};
                const uint4* rowp = (const uint4*)(&Tf[16 * wid + ln][0]);
                #pragma unroll
                for (int kc = 0; kc < 2; ++kc) {
                    f16x8_t A = __builtin_bit_cast(f16x8_t, rowp[4 * kc + kg]);
                    #pragma unroll
                    for (int c = 0; c < 4; ++c)
                        acc[c] = __builtin_amdgcn_mfma_f32_16x16x32_f16(
                            A, Bw[c][kc], acc[c], 0, 0, 0);
                }
                #pragma unroll
                for (int c = 0; c < 4; ++c)
                    #pragma unroll
                    for (int r = 0; r < 4; ++r)
                        G[16 * wid + 4 * kg + r][16 * c + ln] = acc[c][r];
            } else
#endif
            {   // VALU eval (r16-proven): broadcast fdot per site
                for (int m = 0; m < 16; ++m) {
                    int j = 16 * wid + m;
                    if (j < ns) {
                        const uint4* t4 = (const uint4*)Tf[j];
                        float a0 = 0.f, a1 = 0.f, a2_ = 0.f, a3 = 0.f;
                        #pragma unroll
                        for (int q = 0; q < 8; ++q) {
                            uint4 r = t4[q];
                            a0  = fdot(r.x, wh[4*q+0], a0);
                            a1  = fdot(r.y, wh[4*q+1], a1);
                            a2_ = fdot(r.z, wh[4*q+2], a2_);
                            a3  = fdot(r.w, wh[4*q+3], a3);
                        }
                        G[j][lane] = (a0 + a1) + (a2_ + a3);
                    }
                }
            }
            // local scan (wave-local rows): L[m] = alpha*L[m-1] + (G+CB)
            {
                float L = 0.0f;
                for (int m = 0; m < 16; ++m) {
                    int j = 16 * wid + m;
                    if (j < ns) {
                        L = fmaf(alpha, L, G[j][lane] + CB[j][lane]);
                        G[j][lane] = L;
                    }
                }
            }
            __syncthreads();
            // own-combine + fixup + refresh
            {
                float E = h0;                     // h at entry of tile wid
                for (int w = 0; w < wid; ++w)     // tiles before are full
                    E = fmaf(a16, E, G[16 * w + 15][lane]);
                float p = alpha;
                for (int m = 0; m < 16; ++m) {
                    int j = 16 * wid + m;
                    if (j < ns) {
                        float H = fmaf(p, E, G[j][lane]);
                        G[j][lane] = H;
                        if (it < NPIC - 1 && j + 1 < ns)
                            Tf[j + 1][lane] = (__fp16)fast_tanh(H);
                    }
                    p *= alpha;
                }
            }
            __syncthreads();
        }

        // --- odot (wave-local rows) + h0 carry -----------------------------
        for (int m = 0; m < 16; ++m) {
            int j = 16 * wid + m;
            if (j < ns) {
                float t = (float)(__fp16)fast_tanh(G[j][lane]);
                float v = t * wo;
                #pragma unroll
                for (int mm = 32; mm >= 1; mm >>= 1) v += __shfl_xor(v, mm, 64);
                if (lane == 0) out[(size_t)b * SLEN + sbase + j] = v + bo;
            }
        }
        h0 = G[ns - 1][lane];            // cross-wave read (covered by the
        __syncthreads();                 // post-fixup barrier); safety barrier
    }
}

extern "C" void kernel_launch(void* const* d_in, const int* in_sizes, int n_in,
                              void* d_out, int out_size, void* d_ws, size_t ws_size,
                              hipStream_t stream) {
    const float* x     = (const float*)d_in[0];
    const float* W_in  = (const float*)d_in[1];
    const float* b_in  = (const float*)d_in[2];
    const float* W_hh  = (const float*)d_in[3];
    const float* W_ih  = (const float*)d_in[4];
    const float* bias  = (const float*)d_in[5];
    const float* tau   = (const float*)d_in[6];
    const float* W_out = (const float*)d_in[7];
    const float* b_out = (const float*)d_in[8];
    float* out = (float*)d_out;

    lnn_picard_mfma_kernel<<<BATCH, 512, 0, stream>>>(
        x, W_in, b_in, W_hh, W_ih, bias, tau, W_out, b_out, out);
}

// Round 18
// 333.173 us; speedup vs baseline: 1.5282x; 1.1633x over previous
//
#include <hip/hip_runtime.h>

// LiquidNeuralNetwork: B=512, S=1024, IN=16, HID=64, OUT=1.
// r17 (Picard + MFMA eval): 352us, exact (absmax bit-identical). Counters:
// SQ_LDS_BANK_CONFLICT 5.7M (A-loads 16-way: 128B row stride; G stores
// 4-way), LDS 82432B > 80K -> 1 block/CU (2 rounds). 3 sweeps over-
// provisioned (bit-identical => residual far below f16 floor).
//
// Round 18: (a) conflict-free strides: Tf stride 72 f16 (144B), G stride
// 68 f32 (272B) -> every LDS access <=2-way (free, m136). (b) CB moves to
// 16 VGPRs per lane (proj and scan are wave-local) -> LDS 53.2KB ->
// 3 blocks/CU, one round. (c) NPIC 3->2 (kappa~0.01/sweep; residual
// ~2.5e-6, 6x below the 2^-16 f16 floor that absmax sat on all session).
// (d) eval->scan barrier dropped (same-wave LDS dep only, r0-proven).
// MFMA path gated by full integer self-test; VALU fallback kept.

constexpr int HID  = 64;
constexpr int INF  = 16;
constexpr int SLEN = 1024;
constexpr int BATCH = 512;
constexpr int K    = 128;            // chunk steps
constexpr int NPIC = 2;              // Picard sweeps per chunk
constexpr int TFS  = HID + 8;        // Tf row stride (f16): 144 B
constexpr int GS   = HID + 4;        // G row stride (f32): 272 B

typedef __fp16 h2_t   __attribute__((ext_vector_type(2)));
typedef __fp16 f16x8_t __attribute__((ext_vector_type(8)));
typedef float  f32x4_t __attribute__((ext_vector_type(4)));

#if __has_builtin(__builtin_amdgcn_mfma_f32_16x16x32_f16)
#define HAVE_MFMA16 1
#else
#define HAVE_MFMA16 0
#endif

__device__ __forceinline__ float fdot(unsigned a, h2_t w, float acc) {
    return __builtin_amdgcn_fdot2(__builtin_bit_cast(h2_t, a), w, acc, false);
}

__device__ __forceinline__ float fast_tanh(float x) {
    // tanh(x) = 1 - 2/(e^{2x}+1); exact limits at +/-inf, no clamp needed.
    float e = __builtin_amdgcn_exp2f(x * 2.8853900817779268f); // 2*log2(e)
    float r = __builtin_amdgcn_rcpf(e + 1.0f);
    return fmaf(-2.0f, r, 1.0f);
}

// -expm1(-z) by series, exact to ~1e-17 for z ~ 1e-3 (avoids 1-exp cancel)
__device__ __forceinline__ float beta_of(float z) {
    return z * (1.0f - z * (0.5f - z * ((1.0f/6.0f) - z * (1.0f/24.0f))));
}

__global__ __launch_bounds__(512) void lnn_picard2_kernel(
    const float* __restrict__ x,
    const float* __restrict__ W_in,
    const float* __restrict__ b_in,
    const float* __restrict__ W_hh,
    const float* __restrict__ W_ih,
    const float* __restrict__ bias,
    const float* __restrict__ tau,
    const float* __restrict__ W_out,
    const float* __restrict__ b_out,
    float* __restrict__ out)
{
    const int tid  = threadIdx.x;
    const int lane = tid & 63;           // hidden index
    const int wid  = tid >> 6;           // wave id 0..7 (16-site tile each)
    const int b    = blockIdx.x;         // batch index
    const int kg   = lane >> 4;          // k-group 0..3
    const int ln   = lane & 15;          // sub-index 0..15

    __shared__ __fp16 Tf[K][TFS];        // 18 KB: f16 tanh of trajectory
    __shared__ float  G [K][GS];         // 34 KB: eval out, then h after scan
                                         // total ~53.2 KB -> 3 blocks/CU

    // --- per-lane setup -----------------------------------------------------
    float Wc[INF];
    #pragma unroll
    for (int k = 0; k < INF; ++k) Wc[k] = 0.0f;
    float bcomb = 0.0f;
    for (int j = 0; j < HID; ++j) {
        float wij = W_ih[lane * HID + j];
        bcomb = fmaf(wij, b_in[j], bcomb);
        #pragma unroll
        for (int k = 0; k < INF; ++k) Wc[k] = fmaf(wij, W_in[j * INF + k], Wc[k]);
    }
    const float cbase = bcomb + bias[lane];
    const float bo    = b_out[0];
    const float wo    = W_out[lane];

    const float hsub  = 1.0f / 1023.0f;
    const float rtau  = 1.0f / tau[lane];
    const float beta  = beta_of(hsub * rtau);    // 1 - e^{-dt/tau}
    const float alpha = 1.0f - beta;             // e^{-dt/tau}
    float aa2 = alpha * alpha, aa4 = aa2 * aa2, aa8 = aa4 * aa4;
    const float a16 = aa8 * aa8;                 // tile propagator

    // --- MFMA path: fragments + end-to-end integer self-test ---------------
    bool mfok = false;
#if HAVE_MFMA16
    f16x8_t Bw[4][2];                    // B frags: [col-tile c][k-chunk kc]
    {
        // test pattern: Tf[j][i] = ((j*5+i*3)&7)-3 ; Wt(i,m) = ((i*3+m*7)&7)-3
        #pragma unroll
        for (int m = 0; m < 16; ++m) {
            int j = 16 * wid + m;
            Tf[j][lane] = (__fp16)(float)(((j * 5 + lane * 3) & 7) - 3);
        }
        #pragma unroll
        for (int c = 0; c < 4; ++c)
            #pragma unroll
            for (int kc = 0; kc < 2; ++kc) {
                int col = 16 * c + ln;
                #pragma unroll
                for (int e = 0; e < 8; ++e) {
                    int m = 32 * kc + 8 * kg + e;    // our slot->k map
                    Bw[c][kc][e] = (__fp16)(float)(((col * 3 + m * 7) & 7) - 3);
                }
            }
        __syncthreads();
        {   // eval (same code as production): A mirrors the slot->k map
            f32x4_t acc[4];
            #pragma unroll
            for (int c = 0; c < 4; ++c) acc[c] = (f32x4_t){0.f, 0.f, 0.f, 0.f};
            const uint4* rowp = (const uint4*)(&Tf[16 * wid + ln][0]);
            #pragma unroll
            for (int kc = 0; kc < 2; ++kc) {
                f16x8_t A = __builtin_bit_cast(f16x8_t, rowp[4 * kc + kg]);
                #pragma unroll
                for (int c = 0; c < 4; ++c)
                    acc[c] = __builtin_amdgcn_mfma_f32_16x16x32_f16(
                        A, Bw[c][kc], acc[c], 0, 0, 0);
            }
            #pragma unroll
            for (int c = 0; c < 4; ++c)
                #pragma unroll
                for (int r = 0; r < 4; ++r)
                    G[16 * wid + 4 * kg + r][16 * c + ln] = acc[c][r];
        }
        int ok = 1;
        for (int m = 0; m < 16; ++m) {
            int j = 16 * wid + m;
            int ref = 0;
            for (int mm = 0; mm < HID; ++mm)
                ref += (((lane * 3 + mm * 7) & 7) - 3)
                     * (((j * 5 + mm * 3) & 7) - 3);
            ok &= (G[j][lane] == (float)ref);
        }
        mfok = (__syncthreads_and(ok) != 0);
        if (mfok) {
            #pragma unroll
            for (int c = 0; c < 4; ++c) {
                int col = 16 * c + ln;
                float bcol = beta_of(hsub * (1.0f / tau[col]));
                #pragma unroll
                for (int kc = 0; kc < 2; ++kc)
                    #pragma unroll
                    for (int e = 0; e < 8; ++e) {
                        int m = 32 * kc + 8 * kg + e;
                        Bw[c][kc][e] = (__fp16)(W_hh[col * HID + m] * bcol);
                    }
            }
        }
    }
#endif
    // fallback weights (lane's own row, beta-folded, Tf memory order)
    h2_t wh[HID / 2];
    if (!mfok) {
        const float4* w4 = (const float4*)(W_hh + lane * HID);
        #pragma unroll
        for (int q = 0; q < HID / 4; ++q) {
            float4 v = w4[q];
            wh[2*q+0] = __builtin_amdgcn_cvt_pkrtz(v.x * beta, v.y * beta);
            wh[2*q+1] = __builtin_amdgcn_cvt_pkrtz(v.z * beta, v.w * beta);
        }
    }

    if (tid == 0) out[(size_t)b * SLEN] = bo;    // step 0: dt=0, h=0

    float h0 = 0.0f;                     // h at chunk start (all lanes/waves)
    float cbreg[16];                     // wave-local tile's beta*c (VGPRs)

    for (int ch = 0; ch < (SLEN - 1 + K - 1) / K; ++ch) {
        const int sbase = ch * K + 1;
        const int ns    = min(K, (SLEN - 1) - ch * K);   // 128 (last: 127)

        // --- proj (into registers) + trajectory init -----------------------
        {
            __fp16 t0 = (__fp16)fast_tanh(h0);
            #pragma unroll
            for (int m = 0; m < 16; ++m) {
                int j = 16 * wid + m;
                if (j < ns) {
                    const float4* xs =
                        (const float4*)(x + ((size_t)b * SLEN + sbase + j) * INF);
                    float4 p0 = xs[0], p1 = xs[1], p2 = xs[2], p3 = xs[3];
                    float cA = fmaf(p0.x, Wc[0], fmaf(p0.y, Wc[1],
                               fmaf(p0.z, Wc[2], fmaf(p0.w, Wc[3], cbase))));
                    float cB = fmaf(p1.x, Wc[4], fmaf(p1.y, Wc[5],
                               fmaf(p1.z, Wc[6], p1.w * Wc[7])));
                    float cC = fmaf(p2.x, Wc[8], fmaf(p2.y, Wc[9],
                               fmaf(p2.z, Wc[10], p2.w * Wc[11])));
                    float cD = fmaf(p3.x, Wc[12], fmaf(p3.y, Wc[13],
                               fmaf(p3.z, Wc[14], p3.w * Wc[15])));
                    cbreg[m] = ((cA + cB) + (cC + cD)) * beta;
                    Tf[j][lane] = t0;
                }
            }
        }
        __syncthreads();

        // --- Picard sweeps -------------------------------------------------
        for (int it = 0; it < NPIC; ++it) {
            // eval: G[j][i] = sum_m Whh_b[i][m] * Tf[j][m]
#if HAVE_MFMA16
            if (mfok) {
                f32x4_t acc[4];
                #pragma unroll
                for (int c = 0; c < 4; ++c) acc[c] = (f32x4_t){0.f,0.f,0.f,0.f};
                const uint4* rowp = (const uint4*)(&Tf[16 * wid + ln][0]);
                #pragma unroll
                for (int kc = 0; kc < 2; ++kc) {
                    f16x8_t A = __builtin_bit_cast(f16x8_t, rowp[4 * kc + kg]);
                    #pragma unroll
                    for (int c = 0; c < 4; ++c)
                        acc[c] = __builtin_amdgcn_mfma_f32_16x16x32_f16(
                            A, Bw[c][kc], acc[c], 0, 0, 0);
                }
                #pragma unroll
                for (int c = 0; c < 4; ++c)
                    #pragma unroll
                    for (int r = 0; r < 4; ++r)
                        G[16 * wid + 4 * kg + r][16 * c + ln] = acc[c][r];
            } else
#endif
            {   // VALU eval (r16-proven)
                for (int m = 0; m < 16; ++m) {
                    int j = 16 * wid + m;
                    if (j < ns) {
                        const uint4* t4 = (const uint4*)Tf[j];
                        float a0 = 0.f, a1 = 0.f, a2_ = 0.f, a3 = 0.f;
                        #pragma unroll
                        for (int q = 0; q < 8; ++q) {
                            uint4 r = t4[q];
                            a0  = fdot(r.x, wh[4*q+0], a0);
                            a1  = fdot(r.y, wh[4*q+1], a1);
                            a2_ = fdot(r.z, wh[4*q+2], a2_);
                            a3  = fdot(r.w, wh[4*q+3], a3);
                        }
                        G[j][lane] = (a0 + a1) + (a2_ + a3);
                    }
                }
            }
            // local scan (same-wave LDS dep only -> no barrier; r0 idiom)
            {
                float L = 0.0f;
                #pragma unroll
                for (int m = 0; m < 16; ++m) {
                    int j = 16 * wid + m;
                    if (j < ns) {
                        L = fmaf(alpha, L, G[j][lane] + cbreg[m]);
                        G[j][lane] = L;
                    }
                }
            }
            __syncthreads();
            // combine (cross-wave tile-end reads) + fixup + tanh refresh
            {
                float E = h0;                     // h at entry of tile wid
                for (int w = 0; w < wid; ++w)
                    E = fmaf(a16, E, G[16 * w + 15][lane]);
                float p = alpha;
                #pragma unroll
                for (int m = 0; m < 16; ++m) {
                    int j = 16 * wid + m;
                    if (j < ns) {
                        float H = fmaf(p, E, G[j][lane]);
                        G[j][lane] = H;
                        if (it < NPIC - 1 && j + 1 < ns)
                            Tf[j + 1][lane] = (__fp16)fast_tanh(H);
                    }
                    p *= alpha;
                }
            }
            __syncthreads();
        }

        // --- odot (own rows; safe after sweep-end barrier) -----------------
        for (int m = 0; m < 16; ++m) {
            int j = 16 * wid + m;
            if (j < ns) {
                float t = (float)(__fp16)fast_tanh(G[j][lane]);
                float v = t * wo;
                #pragma unroll
                for (int mm = 32; mm >= 1; mm >>= 1) v += __shfl_xor(v, mm, 64);
                if (lane == 0) out[(size_t)b * SLEN + sbase + j] = v + bo;
            }
        }
        h0 = G[ns - 1][lane];            // covered by sweep-end barrier
        __syncthreads();                 // Tf/G safe to overwrite
    }
}

extern "C" void kernel_launch(void* const* d_in, const int* in_sizes, int n_in,
                              void* d_out, int out_size, void* d_ws, size_t ws_size,
                              hipStream_t stream) {
    const float* x     = (const float*)d_in[0];
    const float* W_in  = (const float*)d_in[1];
    const float* b_in  = (const float*)d_in[2];
    const float* W_hh  = (const float*)d_in[3];
    const float* W_ih  = (const float*)d_in[4];
    const float* bias  = (const float*)d_in[5];
    const float* tau   = (const float*)d_in[6];
    const float* W_out = (const float*)d_in[7];
    const float* b_out = (const float*)d_in[8];
    float* out = (float*)d_out;

    lnn_picard2_kernel<<<BATCH, 512, 0, stream>>>(
        x, W_in, b_in, W_hh, W_ih, bias, tau, W_out, b_out, out);
}